// Round 4
// baseline (1006.754 us; speedup 1.0000x reference)
//
#include <hip/hip_runtime.h>
#include <stdint.h>

typedef unsigned short u16;
typedef uint32_t u32;
typedef short s16x8 __attribute__((ext_vector_type(8)));
typedef float f32x4 __attribute__((ext_vector_type(4)));

#define DEV __device__ __forceinline__

// 2*log2(e): tanh(x) = 1 - 2/(exp2(C*x)+1)
#define TSCALE 2.885390082f

DEV float bf2f(u16 h){ union{u32 u; float f;} x; x.u = ((u32)h)<<16; return x.f; }
DEV u16 f2bf(float f){ union{float f; u32 u;} x; x.f = f; u32 u = x.u;
  return (u16)((u + 0x7fffu + ((u>>16)&1u))>>16); }
DEV float bflo(u32 w){ union{u32 u; float f;} x; x.u = w<<16; return x.f; }
DEV float bfhi(u32 w){ union{u32 u; float f;} x; x.u = w & 0xffff0000u; return x.f; }

DEV float exp2_fast(float x){ return __builtin_amdgcn_exp2f(x); }
DEV float rcp_fast(float x){ return __builtin_amdgcn_rcpf(x); }
DEV float tanh2(float x){ float t = exp2_fast(TSCALE*x);
  return fmaf(-2.f, rcp_fast(t + 1.f), 1.f); }
DEV float sig2(float x){ return rcp_fast(1.f + exp2_fast(-1.442695041f*x)); }

// device-coherent (agent-scope, write-through) accessors — exchange stores + flags.
DEV u32   ld_u(const u32* p){ return __hip_atomic_load(p, __ATOMIC_RELAXED, __HIP_MEMORY_SCOPE_AGENT); }
DEV void  st_u(u32* p, u32 v){ __hip_atomic_store(p, v, __ATOMIC_RELAXED, __HIP_MEMORY_SCOPE_AGENT); }

// ---------------- fused prep: all f32->bf16 converts + token gather ----------------
DEV void cvt4(const float* __restrict__ src, u16* __restrict__ dst, int i, float scale){
  float4 v = ((const float4*)src)[i];
  ushort4 o; o.x = f2bf(v.x*scale); o.y = f2bf(v.y*scale); o.z = f2bf(v.z*scale); o.w = f2bf(v.w*scale);
  ((ushort4*)dst)[i] = o;
}
__global__ void prep_all(
    const float* __restrict__ V, const float* __restrict__ Wih, const float* __restrict__ Whh,
    const float* __restrict__ attWw, const float* __restrict__ attUw, const float* __restrict__ projw,
    const float* __restrict__ embed, const int* __restrict__ y,
    u16* __restrict__ Vb, u16* __restrict__ WihB, u16* __restrict__ WhhB,
    u16* __restrict__ attWwB, u16* __restrict__ attUwB, u16* __restrict__ projB,
    u16* __restrict__ embB, u16* __restrict__ Xb)
{
  int blk = blockIdx.x, tid = threadIdx.x;
  if      (blk < 1568)  cvt4(V,     Vb,     blk*256 + tid, 1.0f);
  else if (blk < 2336)  cvt4(Wih,   WihB,   (blk-1568)*256 + tid, 1.0f);
  else if (blk < 3360)  cvt4(Whh,   WhhB,   (blk-2336)*256 + tid, 1.0f);
  else if (blk < 3488)  cvt4(attWw, attWwB, (blk-3360)*256 + tid, TSCALE);
  else if (blk < 3520)  cvt4(attUw, attUwB, (blk-3488)*256 + tid, TSCALE);
  else if (blk < 3648)  cvt4(projw, projB,  (blk-3520)*256 + tid, 1.0f);
  else if (blk < 11148) cvt4(embed, embB,   (blk-3648)*256 + tid, 1.0f);
  else {
    int r = blk - 11148;                 // 0..1983 : row s*64+b
    int s = r>>6, b = r&63;
    int tok = y[b*32 + s];
    Xb[(size_t)r*256 + tid] = f2bf(embed[(size_t)tok*256 + tid]);
  }
}

// ---- extract Wih[:,256:384] as bf16 (2048 x 128) ----
__global__ void prep_wih2b(const float* __restrict__ Wih, u16* __restrict__ Wc){
  int idx = blockIdx.x*256 + threadIdx.x;      // 2048*128 = 262144
  int j = idx>>7, k = idx&127;
  Wc[idx] = f2bf(Wih[(size_t)j*384 + 256 + k]);
}

// ---- repack H2[t][q][b][8] (t=1..31) -> Hl[(s*64+b)][512] row-major ----
__global__ void repack_h(const u16* __restrict__ H2, u16* __restrict__ Hl){
  int r = blockIdx.x;                // 0..1983 : row s*64+b
  int s = r>>6, b = r&63;
  int tid = threadIdx.x;             // 256 threads, each one u32 (2 cols)
  u32 v = *((const u32*)(H2 + (size_t)(s+1)*32768 + (size_t)(tid>>2)*512 + (size_t)b*8) + (tid&3));
  ((u32*)(Hl + (size_t)r*512))[tid] = v;
}

// ---------------- C = A * B^T (+bias) bf16 MFMA GEMM, 64x128 tile ----------------
// mode 0: f32 out; 1: bf16 out; 2: f32 out with row remap (r=s*64+b -> b*31+s)
__global__ __launch_bounds__(256) void gemm_bt(
    const u16* __restrict__ A, int lda,
    const u16* __restrict__ B, int ldb,
    const float* __restrict__ bias1, const float* __restrict__ bias2, float bscale,
    void* __restrict__ C, int ldc,
    int M, int N, int K, int Mt, int mode)
{
  __shared__ __align__(16) u16 As[64*64];
  __shared__ __align__(16) u16 Bs[128*64];
  int nwg = (int)gridDim.x;
  int b0 = blockIdx.x;
  int qq = nwg >> 3, rr = nwg & 7;
  int bswz;
  if (qq == 0) bswz = b0;
  else {
    int xcd = b0 & 7, i = b0 >> 3;
    bswz = (xcd < rr) ? (xcd*(qq+1) + i) : (rr*(qq+1) + (xcd - rr)*qq + i);
  }
  int mt = bswz % Mt, nt = bswz / Mt;
  int m0 = mt*64, n0 = nt*128;
  int tid = threadIdx.x, wave = tid>>6, lane = tid&63;
  int lrow = lane>>3, lcol = (lane&7)*8;
  f32x4 acc[2][4];
  #pragma unroll
  for (int i=0;i<2;i++)
    #pragma unroll
    for (int j=0;j<4;j++) acc[i][j] = (f32x4){0,0,0,0};
  int wm = (wave>>1)*32, wn = (wave&1)*64;
  int fr = lane&15, fk = (lane>>4)*8;
  for (int k0 = 0; k0 < K; k0 += 64) {
    __syncthreads();
    #pragma unroll
    for (int i = 0; i < 2; i++) {
      int ci = wave + i*4;
      int row = ci*8 + lrow;
      const u16* g = A + (size_t)(m0+row)*lda + k0 + lcol;
      __builtin_amdgcn_global_load_lds(
        (const __attribute__((address_space(1))) u32*)g,
        (__attribute__((address_space(3))) u32*)&As[ci*512], 16, 0, 0);
    }
    #pragma unroll
    for (int i = 0; i < 4; i++) {
      int ci = wave + i*4;
      int row = ci*8 + lrow;
      int gr = n0 + row; gr = gr < N ? gr : N-1;
      const u16* g = B + (size_t)gr*ldb + k0 + lcol;
      __builtin_amdgcn_global_load_lds(
        (const __attribute__((address_space(1))) u32*)g,
        (__attribute__((address_space(3))) u32*)&Bs[ci*512], 16, 0, 0);
    }
    __syncthreads();
    #pragma unroll
    for (int kk = 0; kk < 2; kk++) {
      s16x8 af[2], bfv[4];
      #pragma unroll
      for (int mi=0; mi<2; mi++)
        af[mi] = *(const s16x8*)&As[(wm + mi*16 + fr)*64 + kk*32 + fk];
      #pragma unroll
      for (int ni=0; ni<4; ni++)
        bfv[ni] = *(const s16x8*)&Bs[(wn + ni*16 + fr)*64 + kk*32 + fk];
      #pragma unroll
      for (int mi=0; mi<2; mi++)
        #pragma unroll
        for (int ni=0; ni<4; ni++)
          acc[mi][ni] = __builtin_amdgcn_mfma_f32_16x16x32_bf16(af[mi], bfv[ni], acc[mi][ni], 0,0,0);
    }
  }
  #pragma unroll
  for (int mi=0; mi<2; mi++)
    #pragma unroll
    for (int ni=0; ni<4; ni++) {
      int col = n0 + wn + ni*16 + (lane&15);
      if (col >= N) continue;
      float bv = 0.0f;
      if (bias1) bv += bias1[col];
      if (bias2) bv += bias2[col];
      bv *= bscale;
      int rbase = m0 + wm + mi*16 + ((lane>>4)<<2);
      #pragma unroll
      for (int r=0; r<4; r++) {
        int row = rbase + r;
        float v = acc[mi][ni][r] + bv;
        if (mode == 0) ((float*)C)[(size_t)row*ldc + col] = v;
        else if (mode == 1) ((u16*)C)[(size_t)row*ldc + col] = f2bf(v);
        else { int orow = (row&63)*31 + (row>>6); ((float*)C)[(size_t)orow*ldc + col] = v; }
      }
    }
}

// ---------------- C = A * B^T (+bias) bf16 MFMA GEMM, 64x256 tile ----------------
// 4 waves, each owns a 64x64 sub-tile: 32 MFMA per k-step per wave (2x gemm_bt's
// MFMA:stage ratio), half the block count, A staged once per 256 output cols.
__global__ __launch_bounds__(256) void gemm_bt256(
    const u16* __restrict__ A, int lda,
    const u16* __restrict__ B, int ldb,
    const float* __restrict__ bias1, const float* __restrict__ bias2, float bscale,
    void* __restrict__ C, int ldc,
    int M, int N, int K, int Mt, int mode)
{
  __shared__ __align__(16) u16 As[64*64];     // 8 KB
  __shared__ __align__(16) u16 Bs[256*64];    // 32 KB
  int nwg = (int)gridDim.x;
  int b0 = blockIdx.x;
  int qq = nwg >> 3, rr = nwg & 7;
  int bswz;
  if (qq == 0) bswz = b0;
  else {
    int xcd = b0 & 7, i = b0 >> 3;
    bswz = (xcd < rr) ? (xcd*(qq+1) + i) : (rr*(qq+1) + (xcd - rr)*qq + i);
  }
  int mt = bswz % Mt, nt = bswz / Mt;
  int m0 = mt*64, n0 = nt*256;
  int tid = threadIdx.x, wave = tid>>6, lane = tid&63;
  int lrow = lane>>3, lcol = (lane&7)*8;
  f32x4 acc[4][4];
  #pragma unroll
  for (int i=0;i<4;i++)
    #pragma unroll
    for (int j=0;j<4;j++) acc[i][j] = (f32x4){0,0,0,0};
  int fr = lane&15, fk = (lane>>4)*8;
  for (int k0 = 0; k0 < K; k0 += 64) {
    __syncthreads();
    #pragma unroll
    for (int i = 0; i < 2; i++) {          // A: 8 chunks of 8 rows, 2/wave
      int ci = wave*2 + i;
      int row = ci*8 + lrow;
      const u16* g = A + (size_t)(m0+row)*lda + k0 + lcol;
      __builtin_amdgcn_global_load_lds(
        (const __attribute__((address_space(1))) u32*)g,
        (__attribute__((address_space(3))) u32*)&As[ci*512], 16, 0, 0);
    }
    #pragma unroll
    for (int i = 0; i < 8; i++) {          // B: 32 chunks of 8 rows, 8/wave
      int ci = wave*8 + i;
      int row = ci*8 + lrow;
      int gr = n0 + row; gr = gr < N ? gr : N-1;
      const u16* g = B + (size_t)gr*ldb + k0 + lcol;
      __builtin_amdgcn_global_load_lds(
        (const __attribute__((address_space(1))) u32*)g,
        (__attribute__((address_space(3))) u32*)&Bs[ci*512], 16, 0, 0);
    }
    __syncthreads();
    #pragma unroll
    for (int kk = 0; kk < 2; kk++) {
      s16x8 af[4], bfv[4];
      #pragma unroll
      for (int mi=0; mi<4; mi++)
        af[mi] = *(const s16x8*)&As[(mi*16 + fr)*64 + kk*32 + fk];
      #pragma unroll
      for (int ni=0; ni<4; ni++)
        bfv[ni] = *(const s16x8*)&Bs[(wave*64 + ni*16 + fr)*64 + kk*32 + fk];
      #pragma unroll
      for (int mi=0; mi<4; mi++)
        #pragma unroll
        for (int ni=0; ni<4; ni++)
          acc[mi][ni] = __builtin_amdgcn_mfma_f32_16x16x32_bf16(af[mi], bfv[ni], acc[mi][ni], 0,0,0);
    }
  }
  #pragma unroll
  for (int mi=0; mi<4; mi++)
    #pragma unroll
    for (int ni=0; ni<4; ni++) {
      int col = n0 + wave*64 + ni*16 + (lane&15);
      if (col >= N) continue;
      float bv = 0.0f;
      if (bias1) bv += bias1[col];
      if (bias2) bv += bias2[col];
      bv *= bscale;
      int rbase = m0 + mi*16 + ((lane>>4)<<2);
      #pragma unroll
      for (int r=0; r<4; r++) {
        int row = rbase + r;
        float v = acc[mi][ni][r] + bv;
        if (mode == 0) ((float*)C)[(size_t)row*ldc + col] = v;
        else if (mode == 1) ((u16*)C)[(size_t)row*ldc + col] = f2bf(v);
        else { int orow = (row&63)*31 + (row>>6); ((float*)C)[(size_t)orow*ldc + col] = v; }
      }
    }
}

// ---------------- persistent recurrence kernel (64 blocks x 512 thr, role-alternating) ----------------
#define NB 64

// all-report flag barrier: producers drain write-through stores (s_waitcnt 0)
// before posting; each block's flag in its own 64B line; 64 lanes poll 64 lines.
DEV void gbar(u32* flags, int bid, unsigned g){
  __asm__ volatile("" ::: "memory");
  __builtin_amdgcn_s_waitcnt(0);
  __syncthreads();
  if (threadIdx.x == 0) st_u(&flags[bid*16], g);
  if (threadIdx.x < 64) {
    for (;;) {
      u32 a = ld_u(&flags[threadIdx.x*16]);
      if (__all(a >= g)) break;
      __builtin_amdgcn_s_sleep(1);
    }
  }
  __syncthreads();
  __asm__ volatile("" ::: "memory");
}

// 512 threads, 8 waves (2/SIMD):
//   waves 0-3: X' role (af prefetch, pre-fired h-MFMAs, post-bar1 tail) + Y share
//   waves 4-7: hls/Xg staging + Y share
// af/xg MALL loads are issued AFTER sync1 so their latency hides under the wh
// L2 stream instead of being drained by sync1's s_waitcnt vmcnt(0).
__global__ __launch_bounds__(512, 1) void decoder_steps(
    const float* __restrict__ V,      // (64,196,128) f32, cached
    const float* __restrict__ attWb,  // (256) f32 (scaled in-kernel)
    const float* __restrict__ attvw,  // (256) f32
    const float* __restrict__ attvb,  // (1)
    const u16* __restrict__ WhhB,     // (2048,512) bf16
    const u16* __restrict__ attWwB,   // (256,512) bf16, PRE-SCALED by TSCALE
    const u16* __restrict__ WcB,      // (2048,128) bf16 = Wih[:,256:384]
    u16* __restrict__ H2,             // (32,64,64,8) bf16 exchange [t][q][b][d]
    const u16* __restrict__ UV,       // (64,196,256) bf16, PRE-SCALED by TSCALE
    const u16* __restrict__ Xg,       // (31,64,2048) bf16, cached (prior kernel)
    u16* __restrict__ CtxB,           // (31,64,128) bf16 exchange
    u32* __restrict__ flags)
{
  int bid = blockIdx.x, tid = threadIdx.x;
  int wave = tid>>6, lane = tid&63;
  int fr = lane&15, fkq = lane>>4;

  __shared__ __align__(16) u16 Wlds[32][648];   // 32 gate rows x 640 (pad 8)
  __shared__ __align__(16) u16 Xglds[64][32];   // Xg slice [b][gate*8+d]
  __shared__ float hls[512];
  __shared__ float whs[256];
  __shared__ float vws[256];
  __shared__ float esc[200];
  __shared__ float red1;
  __shared__ float part[512];

  // ---- prologue: stage this block's 32 gate rows of [Whh | Wc] into LDS ----
  {
    int r = tid>>4, p = tid&15;                      // 32 rows x 16 threads/row
    int grow = ((r>>3)<<9) + bid*8 + (r&7);          // gate*512 + q*8 + dim
    #pragma unroll
    for (int i=0;i<5;i++){
      int k = p*40 + i*8;
      const u16* src = (k < 512) ? (WhhB + (size_t)grow*512 + k)
                                 : (WcB  + (size_t)grow*128 + (k-512));
      *(s16x8*)&Wlds[r][k] = *(const s16x8*)src;
    }
  }
  if (tid < 256) vws[tid] = attvw[tid];
  float vb = attvb[0];
  float c_reg[4] = {0.f,0.f,0.f,0.f};
  unsigned gen = 0;
  __syncthreads();

  int br = wave*16 + fr;   // batch row this lane owns in the X' MFMA (waves 0-3)

  for (int t = 0; t < 31; t++) {
    // ---- waves 4-7: own-h gather -> hls (only thing sync1 must drain) ----
    if (tid >= 256) {
      int t2 = tid - 256;
      u32 hv = *((const u32*)(H2 + (size_t)t*32768 + (size_t)(t2>>2)*512 + (size_t)bid*8) + (t2&3));
      hls[2*t2]   = bflo(hv);
      hls[2*t2+1] = bfhi(hv);
    }
    __syncthreads();

    // ---- issue MALL prefetches now: they hide under the wh L2 stream ----
    s16x8 af[16];
    s16x8 xg;
    if (tid < 256) {
      const u16* Hbase = H2 + (size_t)t*32768 + (size_t)br*8;
      #pragma unroll
      for (int kt=0;kt<16;kt++) af[kt] = *(const s16x8*)(Hbase + (size_t)(kt*4+fkq)*512);
    } else {
      int t2 = tid - 256;
      xg = *(const s16x8*)(Xg + (size_t)t*131072 + (size_t)(t2>>2)*2048 + (size_t)(t2&3)*512 + (size_t)bid*8);
    }

    // ---- wh (pre-scaled): thread pair (a=tid>>1) splits k in halves ----
    {
      int a_ = tid>>1, kh = (tid&1)*256;
      const u32* wr = (const u32*)(attWwB + (size_t)a_*512 + kh);
      float acc = (tid&1) ? 0.f : TSCALE * attWb[a_];
      #pragma unroll 4
      for (int k=0;k<256;k+=8){
        u32 w0 = wr[(k>>1)+0], w1 = wr[(k>>1)+1], w2 = wr[(k>>1)+2], w3 = wr[(k>>1)+3];
        float4 h0 = *(const float4*)&hls[kh+k];
        float4 h1 = *(const float4*)&hls[kh+k+4];
        acc = fmaf(bflo(w0), h0.x, acc); acc = fmaf(bfhi(w0), h0.y, acc);
        acc = fmaf(bflo(w1), h0.z, acc); acc = fmaf(bfhi(w1), h0.w, acc);
        acc = fmaf(bflo(w2), h1.x, acc); acc = fmaf(bfhi(w2), h1.y, acc);
        acc = fmaf(bflo(w3), h1.z, acc); acc = fmaf(bfhi(w3), h1.w, acc);
      }
      acc += __shfl_xor(acc, 1);
      if (!(tid&1)) whs[a_] = acc;
    }

    // ---- waves 0-3: fire h-part MFMAs into matrix pipe (consumed post-bar1) ----
    f32x4 a0 = (f32x4){0,0,0,0}, a1 = (f32x4){0,0,0,0};
    if (tid < 256) {
      #pragma unroll
      for (int kt=0;kt<16;kt++){
        s16x8 b0 = *(const s16x8*)&Wlds[fr][kt*32 + fkq*8];
        s16x8 b1 = *(const s16x8*)&Wlds[16+fr][kt*32 + fkq*8];
        a0 = __builtin_amdgcn_mfma_f32_16x16x32_bf16(af[kt], b0, a0, 0,0,0);
        a1 = __builtin_amdgcn_mfma_f32_16x16x32_bf16(af[kt], b1, a1, 0,0,0);
      }
      __builtin_amdgcn_sched_barrier(0);
    }
    __syncthreads();

    // ---- scores: half-row per thread (n=tid>>1, 128 dims), shfl pair-combine.
    //      no max-sub: |e| <= sum|vw| ~ 4.1 by construction ----
    if (tid < 392) {
      int n = tid>>1, kh = (tid&1)*128;
      const u32* uvp = (const u32*)(UV + ((size_t)bid*196 + n)*256 + kh);
      float e0 = 0.0f, e1 = 0.0f;
      #pragma unroll 4
      for (int a = 0; a < 128; a += 4) {
        u32 uw0 = uvp[(a>>1)], uw1 = uvp[(a>>1)+1];
        float4 w4 = *(const float4*)&whs[kh+a];
        float4 v4 = *(const float4*)&vws[kh+a];
        float t0 = exp2_fast(w4.x + bflo(uw0));
        float t1 = exp2_fast(w4.y + bfhi(uw0));
        float t2 = exp2_fast(w4.z + bflo(uw1));
        float t3 = exp2_fast(w4.w + bfhi(uw1));
        e0 = fmaf(v4.x, fmaf(-2.f, rcp_fast(t0+1.f), 1.f), e0);
        e1 = fmaf(v4.y, fmaf(-2.f, rcp_fast(t1+1.f), 1.f), e1);
        e0 = fmaf(v4.z, fmaf(-2.f, rcp_fast(t2+1.f), 1.f), e0);
        e1 = fmaf(v4.w, fmaf(-2.f, rcp_fast(t3+1.f), 1.f), e1);
      }
      float e = e0 + e1;
      e += __shfl_xor(e, 1);
      if (!(tid&1)) esc[n] = exp2_fast(1.442695041f*(e + vb));
    }
    // stage Xg -> LDS (waves 4-7; consumed post-bar1, ordered by gbar's syncthreads)
    if (tid >= 256) {
      int t2 = tid - 256;
      *(s16x8*)&Xglds[t2>>2][(t2&3)*8] = xg;
    }
    __syncthreads();

    // ---- sum (wave 0) runs concurrently with 4-way ctx partials (all waves) ----
    if (tid < 64) {
      float s = esc[tid] + esc[64+tid] + esc[128+tid];
      if (tid < 4)  s += esc[192+tid];
      #pragma unroll
      for (int off=32; off>=1; off>>=1) s += __shfl_xor(s, off);
      if (tid==0) red1 = s;
    }
    {
      int k = tid&127, q4 = tid>>7;
      const float* vp = V + ((size_t)bid*196 + q4*49)*128 + k;
      float a = 0.f;
      for (int n2=0; n2<49; n2++) a = fmaf(esc[q4*49+n2], vp[(size_t)n2*128], a);
      part[tid] = a;
    }
    __syncthreads();

    // ---- combine + normalize + publish ctx (bf16 pairs) ----
    if (tid < 64) {
      float inv = rcp_fast(red1);
      float c0 = (part[2*tid]   + part[128+2*tid] + part[256+2*tid] + part[384+2*tid]) * inv;
      float c1 = (part[2*tid+1] + part[129+2*tid] + part[257+2*tid] + part[385+2*tid]) * inv;
      u32 pk = (u32)f2bf(c0) | ((u32)f2bf(c1) << 16);
      st_u((u32*)(CtxB + (size_t)t*8192 + (size_t)bid*128) + tid, pk);
    }
    gen++; gbar(flags, bid, gen);

    // ---- X' tail (waves 0-3): ctx MFMAs + LSTM pointwise ----
    if (tid < 256) {
      const u16* Crow = CtxB + (size_t)t*8192 + (size_t)br*128 + fkq*8;
      #pragma unroll
      for (int kt=0;kt<4;kt++){
        s16x8 cf = *(const s16x8*)(Crow + kt*32);
        s16x8 b0 = *(const s16x8*)&Wlds[fr][(16+kt)*32 + fkq*8];
        s16x8 b1 = *(const s16x8*)&Wlds[16+fr][(16+kt)*32 + fkq*8];
        a0 = __builtin_amdgcn_mfma_f32_16x16x32_bf16(cf, b0, a0, 0,0,0);
        a1 = __builtin_amdgcn_mfma_f32_16x16x32_bf16(cf, b1, a1, 0,0,0);
      }
      // acc mapping: col c=lane&15 -> gate row; row = wave*16 + fkq*4 + r -> batch
      int c = fr;
      int xr0 = ((c>>3)&1)*8 + (c&7);          // Xglds row for tile0 (i|f)
      float v0[4], v1[4], s0[4], s1[4];
      #pragma unroll
      for (int r=0;r<4;r++){
        int b_r = wave*16 + fkq*4 + r;
        v0[r] = a0[r] + bf2f(Xglds[b_r][xr0]);        // i (c<8) / f (c>=8)
        v1[r] = a1[r] + bf2f(Xglds[b_r][16+xr0]);     // g (c<8) / o (c>=8)
      }
      #pragma unroll
      for (int r=0;r<4;r++){ s0[r] = __shfl_xor(v0[r], 8); s1[r] = __shfl_xor(v1[r], 8); }
      if (c < 8) {
        #pragma unroll
        for (int r=0;r<4;r++){
          int b_r = wave*16 + fkq*4 + r;
          float ig = sig2(v0[r]);
          float fg = sig2(s0[r]);
          float gg = tanh2(v1[r]);
          float og = sig2(s1[r]);
          float cn = fmaf(fg, c_reg[r], ig*gg);
          c_reg[r] = cn;
          float hvv = og * tanh2(cn);
          float hp = __shfl_xor(hvv, 1);              // partner dim (c^1)
          if (!(c&1)) {
            u32 pk = (u32)f2bf(hvv) | ((u32)f2bf(hp) << 16);
            st_u((u32*)(H2 + (size_t)(t+1)*32768 + (size_t)bid*512 + (size_t)b_r*8) + (c>>1), pk);
          }
        }
      }
    }
    if (t < 30) { gen++; gbar(flags, bid, gen); }
  }
}

// ---------------- workspace offsets (bytes, 256-aligned) ----------------
#define OFF_H    1024u           // 2,097,152  bf16 H2 (32,64,64,8); slot0 zeroed
#define OFF_UV   2098176u        // 6,422,528  bf16 (64,196,256)
#define OFF_X    8520704u        // 1,015,808  bf16 (1984,256)
#define OFF_XG   9536512u        // 8,126,464  bf16 (31,64,2048); Hl 2MB overlay post-decoder
#define OFF_GH   17662976u       // 15,360,000 bf16 embed
#define OFF_EMB  OFF_GH
#define OFF_WH   33915904u       // flags 4KB + ctxB (31,64,128) bf16 at +8192
#define OFF_E    35947520u       // 1,015,808  bf16 (1984,256)
#define OFF_VB   36963328u       // 3,211,264  bf16 V (pre-decoder); WcB bf16 512KB overlay
#define OFF_WIH  40174592u       // 1,572,864  bf16 Wih
#define OFF_WHH  41747456u       // 2,097,152  bf16 Whh
#define OFF_AWW  43844608u       // 262,144    bf16 attWw
#define OFF_AUW  44106752u       // 65,536     bf16 attUw
#define OFF_PRJ  44172288u       // 262,144    bf16 projw  -> end 44,434,432

extern "C" void kernel_launch(void* const* d_in, const int* in_sizes, int n_in,
                              void* d_out, int out_size, void* d_ws, size_t ws_size,
                              hipStream_t stream)
{
  const float* V      = (const float*)d_in[0];
  const int*   y      = (const int*)  d_in[1];
  const float* embed  = (const float*)d_in[2];
  const float* attWw  = (const float*)d_in[3];
  const float* attWb  = (const float*)d_in[4];
  const float* attUw  = (const float*)d_in[5];
  const float* attUb  = (const float*)d_in[6];
  const float* attvw  = (const float*)d_in[7];
  const float* attvb  = (const float*)d_in[8];
  const float* Wih    = (const float*)d_in[9];
  const float* Whh    = (const float*)d_in[10];
  const float* bih    = (const float*)d_in[11];
  const float* bhh    = (const float*)d_in[12];
  const float* projw  = (const float*)d_in[13];
  float* out = (float*)d_out;
  char* ws = (char*)d_ws;

  u16*   H2   = (u16*)  (ws + OFF_H);
  u16*   UVb  = (u16*)  (ws + OFF_UV);
  u16*   Xb   = (u16*)  (ws + OFF_X);
  u16*   Xg   = (u16*)  (ws + OFF_XG);
  u16*   Hl   = (u16*)  (ws + OFF_XG);   // reuses Xg region after decoder
  u32*   flags= (u32*)  (ws + OFF_WH);
  u16*   CtxB = (u16*)  (ws + OFF_WH + 8192);
  u16*   E    = (u16*)  (ws + OFF_E);
  u16*   Vb   = (u16*)  (ws + OFF_VB);
  u16*   WcB  = (u16*)  (ws + OFF_VB);   // reuses Vb space after UV gemm
  u16*   embB = (u16*)  (ws + OFF_EMB);
  u16*   WihB = (u16*)  (ws + OFF_WIH);
  u16*   WhhB = (u16*)  (ws + OFF_WHH);
  u16*   attWwB = (u16*)(ws + OFF_AWW);
  u16*   attUwB = (u16*)(ws + OFF_AUW);
  u16*   projB  = (u16*)(ws + OFF_PRJ);

  // zero H2 slot 0 (h0 = 0) and flags — re-done every call (ws is re-poisoned)
  hipMemsetAsync(ws + OFF_H, 0, 65536, stream);
  hipMemsetAsync(ws + OFF_WH, 0, 4096, stream);

  // all f32->bf16 converts + token gather in ONE dispatch (att weights pre-scaled)
  prep_all<<<13132, 256, 0, stream>>>(V, Wih, Whh, attWw, attUw, projw, embed, y,
                                      Vb, WihB, WhhB, attWwB, attUwB, projB, embB, Xb);

  // UV = TSCALE*(V @ attUw^T + attUb)  (bf16 out)   M=12544 N=256 K=128
  gemm_bt256<<<196, 256, 0, stream>>>(Vb, 128, attUwB, 128, attUb, nullptr, TSCALE,
                                      UVb, 256, 12544, 256, 128, 196, 1);
  // WcB = bf16(Wih[:,256:384]) (overwrites Vb region — stream-ordered after UV gemm)
  prep_wih2b<<<1024, 256, 0, stream>>>(Wih, WcB);
  // Xg = X @ Wih[:, :256]^T + bih + bhh  (bf16 out)   M=1984 N=2048 K=256
  gemm_bt256<<<31*8, 256, 0, stream>>>(Xb, 256, WihB, 384, bih, bhh, 1.0f,
                                       Xg, 2048, 1984, 2048, 256, 31, 1);

  decoder_steps<<<NB, 512, 0, stream>>>(V, attWb, attvw, attvb,
      WhhB, attWwB, WcB, H2, UVb, Xg, CtxB, flags);

  // H2 -> row-major Hl (1984,512) for the projection GEMM (overlays dead Xg)
  repack_h<<<1984, 256, 0, stream>>>(H2, Hl);

  // E = Hl @ projw^T (bf16 out)   M=1984 N=256 K=512
  gemm_bt<<<31*2, 256, 0, stream>>>(Hl, 512, projB, 512, nullptr, nullptr, 1.0f,
                                    E, 256, 1984, 256, 512, 31, 1);
  // logits = E @ embed^T -> d_out f32 with (s,b)->(b,s) row remap   M=1984 N=30000 K=256
  gemm_bt256<<<31*118, 256, 0, stream>>>(E, 256, embB, 256, nullptr, nullptr, 1.0f,
                                         out, 30000, 1984, 30000, 256, 31, 2);
}

// Round 5
// 1000.407 us; speedup vs baseline: 1.0063x; 1.0063x over previous
//
#include <hip/hip_runtime.h>
#include <stdint.h>

typedef unsigned short u16;
typedef uint32_t u32;
typedef short s16x8 __attribute__((ext_vector_type(8)));
typedef float f32x4 __attribute__((ext_vector_type(4)));

#define DEV __device__ __forceinline__

// 2*log2(e): tanh(x) = 1 - 2/(exp2(C*x)+1)
#define TSCALE 2.885390082f

DEV float bf2f(u16 h){ union{u32 u; float f;} x; x.u = ((u32)h)<<16; return x.f; }
DEV u16 f2bf(float f){ union{float f; u32 u;} x; x.f = f; u32 u = x.u;
  return (u16)((u + 0x7fffu + ((u>>16)&1u))>>16); }
DEV float bflo(u32 w){ union{u32 u; float f;} x; x.u = w<<16; return x.f; }
DEV float bfhi(u32 w){ union{u32 u; float f;} x; x.u = w & 0xffff0000u; return x.f; }

DEV float exp2_fast(float x){ return __builtin_amdgcn_exp2f(x); }
DEV float rcp_fast(float x){ return __builtin_amdgcn_rcpf(x); }
DEV float tanh2(float x){ float t = exp2_fast(TSCALE*x);
  return fmaf(-2.f, rcp_fast(t + 1.f), 1.f); }
DEV float sig2(float x){ return rcp_fast(1.f + exp2_fast(-1.442695041f*x)); }

// device-coherent (agent-scope, write-through) accessors — exchange stores + flags.
DEV u32   ld_u(const u32* p){ return __hip_atomic_load(p, __ATOMIC_RELAXED, __HIP_MEMORY_SCOPE_AGENT); }
DEV void  st_u(u32* p, u32 v){ __hip_atomic_store(p, v, __ATOMIC_RELAXED, __HIP_MEMORY_SCOPE_AGENT); }

// ---------------- fused prep: all f32->bf16 converts + token gather ----------------
DEV void cvt4(const float* __restrict__ src, u16* __restrict__ dst, int i, float scale){
  float4 v = ((const float4*)src)[i];
  ushort4 o; o.x = f2bf(v.x*scale); o.y = f2bf(v.y*scale); o.z = f2bf(v.z*scale); o.w = f2bf(v.w*scale);
  ((ushort4*)dst)[i] = o;
}
__global__ void prep_all(
    const float* __restrict__ V, const float* __restrict__ Wih, const float* __restrict__ Whh,
    const float* __restrict__ attWw, const float* __restrict__ attUw, const float* __restrict__ projw,
    const float* __restrict__ embed, const int* __restrict__ y,
    u16* __restrict__ Vb, u16* __restrict__ WihB, u16* __restrict__ WhhB,
    u16* __restrict__ attWwB, u16* __restrict__ attUwB, u16* __restrict__ projB,
    u16* __restrict__ embB, u16* __restrict__ Xb)
{
  int blk = blockIdx.x, tid = threadIdx.x;
  if      (blk < 1568)  cvt4(V,     Vb,     blk*256 + tid, 1.0f);
  else if (blk < 2336)  cvt4(Wih,   WihB,   (blk-1568)*256 + tid, 1.0f);
  else if (blk < 3360)  cvt4(Whh,   WhhB,   (blk-2336)*256 + tid, 1.0f);
  else if (blk < 3488)  cvt4(attWw, attWwB, (blk-3360)*256 + tid, TSCALE);
  else if (blk < 3520)  cvt4(attUw, attUwB, (blk-3488)*256 + tid, TSCALE);
  else if (blk < 3648)  cvt4(projw, projB,  (blk-3520)*256 + tid, 1.0f);
  else if (blk < 11148) cvt4(embed, embB,   (blk-3648)*256 + tid, 1.0f);
  else {
    int r = blk - 11148;                 // 0..1983 : row s*64+b
    int s = r>>6, b = r&63;
    int tok = y[b*32 + s];
    Xb[(size_t)r*256 + tid] = f2bf(embed[(size_t)tok*256 + tid]);
  }
}

// ---- extract Wih[:,256:384] as bf16 (2048 x 128) ----
__global__ void prep_wih2b(const float* __restrict__ Wih, u16* __restrict__ Wc){
  int idx = blockIdx.x*256 + threadIdx.x;      // 2048*128 = 262144
  int j = idx>>7, k = idx&127;
  Wc[idx] = f2bf(Wih[(size_t)j*384 + 256 + k]);
}

// ---- repack H2[t][q][b][8] (t=1..31) -> Hl[(s*64+b)][512] row-major ----
__global__ void repack_h(const u16* __restrict__ H2, u16* __restrict__ Hl){
  int r = blockIdx.x;                // 0..1983 : row s*64+b
  int s = r>>6, b = r&63;
  int tid = threadIdx.x;             // 256 threads, each one u32 (2 cols)
  u32 v = *((const u32*)(H2 + (size_t)(s+1)*32768 + (size_t)(tid>>2)*512 + (size_t)b*8) + (tid&3));
  ((u32*)(Hl + (size_t)r*512))[tid] = v;
}

// ---------------- C = A * B^T (+bias) bf16 MFMA GEMM, 64x128 tile ----------------
// mode 0: f32 out; 1: bf16 out; 2: f32 out with row remap (r=s*64+b -> b*31+s)
// XCD-bijective block swizzle (m204): contiguous bid-ranges per XCD -> L2 locality.
__global__ __launch_bounds__(256) void gemm_bt(
    const u16* __restrict__ A, int lda,
    const u16* __restrict__ B, int ldb,
    const float* __restrict__ bias1, const float* __restrict__ bias2, float bscale,
    void* __restrict__ C, int ldc,
    int M, int N, int K, int Mt, int mode)
{
  __shared__ __align__(16) u16 As[64*64];
  __shared__ __align__(16) u16 Bs[128*64];
  int nwg = (int)gridDim.x;
  int b0 = blockIdx.x;
  int qq = nwg >> 3, rr = nwg & 7;
  int bswz;
  if (qq == 0) bswz = b0;
  else {
    int xcd = b0 & 7, i = b0 >> 3;
    bswz = (xcd < rr) ? (xcd*(qq+1) + i) : (rr*(qq+1) + (xcd - rr)*qq + i);
  }
  int mt = bswz % Mt, nt = bswz / Mt;
  int m0 = mt*64, n0 = nt*128;
  int tid = threadIdx.x, wave = tid>>6, lane = tid&63;
  int lrow = lane>>3, lcol = (lane&7)*8;
  f32x4 acc[2][4];
  #pragma unroll
  for (int i=0;i<2;i++)
    #pragma unroll
    for (int j=0;j<4;j++) acc[i][j] = (f32x4){0,0,0,0};
  int wm = (wave>>1)*32, wn = (wave&1)*64;
  int fr = lane&15, fk = (lane>>4)*8;
  for (int k0 = 0; k0 < K; k0 += 64) {
    __syncthreads();
    #pragma unroll
    for (int i = 0; i < 2; i++) {
      int ci = wave + i*4;
      int row = ci*8 + lrow;
      const u16* g = A + (size_t)(m0+row)*lda + k0 + lcol;
      __builtin_amdgcn_global_load_lds(
        (const __attribute__((address_space(1))) u32*)g,
        (__attribute__((address_space(3))) u32*)&As[ci*512], 16, 0, 0);
    }
    #pragma unroll
    for (int i = 0; i < 4; i++) {
      int ci = wave + i*4;
      int row = ci*8 + lrow;
      int gr = n0 + row; gr = gr < N ? gr : N-1;
      const u16* g = B + (size_t)gr*ldb + k0 + lcol;
      __builtin_amdgcn_global_load_lds(
        (const __attribute__((address_space(1))) u32*)g,
        (__attribute__((address_space(3))) u32*)&Bs[ci*512], 16, 0, 0);
    }
    __syncthreads();
    #pragma unroll
    for (int kk = 0; kk < 2; kk++) {
      s16x8 af[2], bfv[4];
      #pragma unroll
      for (int mi=0; mi<2; mi++)
        af[mi] = *(const s16x8*)&As[(wm + mi*16 + fr)*64 + kk*32 + fk];
      #pragma unroll
      for (int ni=0; ni<4; ni++)
        bfv[ni] = *(const s16x8*)&Bs[(wn + ni*16 + fr)*64 + kk*32 + fk];
      #pragma unroll
      for (int mi=0; mi<2; mi++)
        #pragma unroll
        for (int ni=0; ni<4; ni++)
          acc[mi][ni] = __builtin_amdgcn_mfma_f32_16x16x32_bf16(af[mi], bfv[ni], acc[mi][ni], 0,0,0);
    }
  }
  #pragma unroll
  for (int mi=0; mi<2; mi++)
    #pragma unroll
    for (int ni=0; ni<4; ni++) {
      int col = n0 + wn + ni*16 + (lane&15);
      if (col >= N) continue;
      float bv = 0.0f;
      if (bias1) bv += bias1[col];
      if (bias2) bv += bias2[col];
      bv *= bscale;
      int rbase = m0 + wm + mi*16 + ((lane>>4)<<2);
      #pragma unroll
      for (int r=0; r<4; r++) {
        int row = rbase + r;
        float v = acc[mi][ni][r] + bv;
        if (mode == 0) ((float*)C)[(size_t)row*ldc + col] = v;
        else if (mode == 1) ((u16*)C)[(size_t)row*ldc + col] = f2bf(v);
        else { int orow = (row&63)*31 + (row>>6); ((float*)C)[(size_t)orow*ldc + col] = v; }
      }
    }
}

// ---------------- persistent recurrence kernel (64 blocks x 512 thr) ----------------
#define NB 64

// all-report flag barrier: producers drain write-through stores (s_waitcnt 0)
// before posting; each block's flag in its own 64B line; 64 lanes poll 64 lines.
DEV void gbar(u32* flags, int bid, unsigned g){
  __asm__ volatile("" ::: "memory");
  __builtin_amdgcn_s_waitcnt(0);
  __syncthreads();
  if (threadIdx.x == 0) st_u(&flags[bid*16], g);
  if (threadIdx.x < 64) {
    for (;;) {
      u32 a = ld_u(&flags[threadIdx.x*16]);
      if (__all(a >= g)) break;
      __builtin_amdgcn_s_sleep(1);
    }
  }
  __syncthreads();
  __asm__ volatile("" ::: "memory");
}

// 512 threads, 8 waves (2/SIMD). X' re-sharded: 8 waves x ONE 16x16 output tile
// (4 batch-tiles x 2 gate-tiles); W B-fragments are t-invariant and live in
// REGISTERS (20 x s16x8 per wave) -> no LDS B-operand reads (kills the 8.7M
// bank conflicts), all 8 waves issue MFMAs. Gate recombination via 9KB glds.
__global__ __launch_bounds__(512, 2) void decoder_steps(
    const float* __restrict__ V,      // (64,196,128) f32, cached
    const float* __restrict__ attWb,  // (256) f32 (scaled in-kernel)
    const float* __restrict__ attvw,  // (256) f32
    const float* __restrict__ attvb,  // (1)
    const u16* __restrict__ WhhB,     // (2048,512) bf16
    const u16* __restrict__ attWwB,   // (256,512) bf16, PRE-SCALED by TSCALE
    const u16* __restrict__ WcB,      // (2048,128) bf16 = Wih[:,256:384]
    u16* __restrict__ H2,             // (32,64,64,8) bf16 exchange [t][q][b][d]
    const u16* __restrict__ UV,       // (64,196,256) bf16, PRE-SCALED by TSCALE
    const u16* __restrict__ Xg,       // (31,64,2048) bf16, cached (prior kernel)
    u16* __restrict__ CtxB,           // (31,64,128) bf16 exchange
    u32* __restrict__ flags)
{
  int bid = blockIdx.x, tid = threadIdx.x;
  int wave = tid>>6, lane = tid&63;
  int fr = lane&15, fkq = lane>>4;
  int gsel = wave&1, bsel = wave>>1;     // gate-tile, batch-tile of this wave
  int b2 = tid>>3, dd = tid&7;           // pointwise ownership: (batch, dim)

  __shared__ float hls[512];
  __shared__ float whs[256];
  __shared__ float vws[256];
  __shared__ float esc[200];
  __shared__ float red1;
  __shared__ float part[512];
  __shared__ float glds[64][36];         // gates exchange [batch][gate*8+d], pad->2-way

  // ---- persistent B-fragments (t-invariant): this wave's 16 gate rows ----
  // local gate row r32 = gsel*16 + fr -> global row (r32>>3)*512 + bid*8 + (r32&7)
  int r32 = gsel*16 + fr;
  int grow = ((r32>>3)<<9) + bid*8 + (r32&7);
  s16x8 bfrag[20];
  #pragma unroll
  for (int kt=0;kt<16;kt++)
    bfrag[kt] = *(const s16x8*)&WhhB[(size_t)grow*512 + kt*32 + fkq*8];
  #pragma unroll
  for (int kt=0;kt<4;kt++)
    bfrag[16+kt] = *(const s16x8*)&WcB[(size_t)grow*128 + kt*32 + fkq*8];

  if (tid < 256) vws[tid] = attvw[tid];
  float vb = attvb[0];
  float c_reg = 0.f;
  unsigned gen = 0;
  __syncthreads();

  int br = bsel*16 + fr;   // batch row this lane owns in the MFMA A-operand

  for (int t = 0; t < 31; t++) {
    // ---- phase 1: issue ALL MALL prefetches BEFORE sync1 (they complete during
    // hls drain + wh; round-4 A/B showed post-sync1 issue serializes behind wh) ----
    s16x8 af[16];
    const u16* Hbase = H2 + (size_t)t*32768 + (size_t)br*8;
    #pragma unroll
    for (int kt=0;kt<16;kt++) af[kt] = *(const s16x8*)(Hbase + (size_t)(kt*4+fkq)*512);
    u16 xr0, xr1, xr2, xr3;
    { const u16* xp = Xg + (size_t)t*131072 + (size_t)b2*2048 + bid*8 + dd;
      xr0 = xp[0]; xr1 = xp[512]; xr2 = xp[1024]; xr3 = xp[1536]; }
    if (tid >= 256) {
      int t2 = tid - 256;
      u32 hv = *((const u32*)(H2 + (size_t)t*32768 + (size_t)(t2>>2)*512 + (size_t)bid*8) + (t2&3));
      hls[2*t2]   = bflo(hv);
      hls[2*t2+1] = bfhi(hv);
    }
    __syncthreads();

    // ---- wh (pre-scaled): thread pair (a=tid>>1) splits k in halves ----
    {
      int a_ = tid>>1, kh = (tid&1)*256;
      const u32* wr = (const u32*)(attWwB + (size_t)a_*512 + kh);
      float acc = (tid&1) ? 0.f : TSCALE * attWb[a_];
      #pragma unroll 4
      for (int k=0;k<256;k+=8){
        u32 w0 = wr[(k>>1)+0], w1 = wr[(k>>1)+1], w2 = wr[(k>>1)+2], w3 = wr[(k>>1)+3];
        float4 h0 = *(const float4*)&hls[kh+k];
        float4 h1 = *(const float4*)&hls[kh+k+4];
        acc = fmaf(bflo(w0), h0.x, acc); acc = fmaf(bfhi(w0), h0.y, acc);
        acc = fmaf(bflo(w1), h0.z, acc); acc = fmaf(bfhi(w1), h0.w, acc);
        acc = fmaf(bflo(w2), h1.x, acc); acc = fmaf(bfhi(w2), h1.y, acc);
        acc = fmaf(bflo(w3), h1.z, acc); acc = fmaf(bfhi(w3), h1.w, acc);
      }
      acc += __shfl_xor(acc, 1);
      if (!(tid&1)) whs[a_] = acc;
    }

    // ---- all 8 waves: fire h-part MFMAs (reg operands only, consumed post-bar1) ----
    f32x4 a0 = (f32x4){0,0,0,0};
    #pragma unroll
    for (int kt=0;kt<16;kt++)
      a0 = __builtin_amdgcn_mfma_f32_16x16x32_bf16(af[kt], bfrag[kt], a0, 0,0,0);
    __builtin_amdgcn_sched_barrier(0);
    __syncthreads();

    // ---- scores: half-row per thread (n=tid>>1, 128 dims), shfl pair-combine.
    //      no max-sub: |e| <= sum|vw| ~ 4.1 by construction ----
    if (tid < 392) {
      int n = tid>>1, kh = (tid&1)*128;
      const u32* uvp = (const u32*)(UV + ((size_t)bid*196 + n)*256 + kh);
      float e0 = 0.0f, e1 = 0.0f;
      #pragma unroll 4
      for (int a = 0; a < 128; a += 4) {
        u32 uw0 = uvp[(a>>1)], uw1 = uvp[(a>>1)+1];
        float4 w4 = *(const float4*)&whs[kh+a];
        float4 v4 = *(const float4*)&vws[kh+a];
        float t0 = exp2_fast(w4.x + bflo(uw0));
        float t1 = exp2_fast(w4.y + bfhi(uw0));
        float t2 = exp2_fast(w4.z + bflo(uw1));
        float t3 = exp2_fast(w4.w + bfhi(uw1));
        e0 = fmaf(v4.x, fmaf(-2.f, rcp_fast(t0+1.f), 1.f), e0);
        e1 = fmaf(v4.y, fmaf(-2.f, rcp_fast(t1+1.f), 1.f), e1);
        e0 = fmaf(v4.z, fmaf(-2.f, rcp_fast(t2+1.f), 1.f), e0);
        e1 = fmaf(v4.w, fmaf(-2.f, rcp_fast(t3+1.f), 1.f), e1);
      }
      float e = e0 + e1;
      e += __shfl_xor(e, 1);
      if (!(tid&1)) esc[n] = exp2_fast(1.442695041f*(e + vb));
    }
    __syncthreads();

    // ---- sum (wave 0) runs concurrently with 4-way ctx partials (all waves) ----
    if (tid < 64) {
      float s = esc[tid] + esc[64+tid] + esc[128+tid];
      if (tid < 4)  s += esc[192+tid];
      #pragma unroll
      for (int off=32; off>=1; off>>=1) s += __shfl_xor(s, off);
      if (tid==0) red1 = s;
    }
    {
      int k = tid&127, q4 = tid>>7;
      const float* vp = V + ((size_t)bid*196 + q4*49)*128 + k;
      float a = 0.f;
      for (int n2=0; n2<49; n2++) a = fmaf(esc[q4*49+n2], vp[(size_t)n2*128], a);
      part[tid] = a;
    }
    __syncthreads();

    // ---- combine + normalize + publish ctx (bf16 pairs) ----
    if (tid < 64) {
      float inv = rcp_fast(red1);
      float c0 = (part[2*tid]   + part[128+2*tid] + part[256+2*tid] + part[384+2*tid]) * inv;
      float c1 = (part[2*tid+1] + part[129+2*tid] + part[257+2*tid] + part[385+2*tid]) * inv;
      u32 pk = (u32)f2bf(c0) | ((u32)f2bf(c1) << 16);
      st_u((u32*)(CtxB + (size_t)t*8192 + (size_t)bid*128) + tid, pk);
    }
    gen++; gbar(flags, bid, gen);

    // ---- X' tail: ctx MFMAs (reg B) -> gates to glds ----
    {
      const u16* Crow = CtxB + (size_t)t*8192 + (size_t)br*128 + fkq*8;
      #pragma unroll
      for (int kt=0;kt<4;kt++){
        s16x8 cf = *(const s16x8*)(Crow + kt*32);
        a0 = __builtin_amdgcn_mfma_f32_16x16x32_bf16(cf, bfrag[16+kt], a0, 0,0,0);
      }
      #pragma unroll
      for (int r=0;r<4;r++)
        glds[bsel*16 + fkq*4 + r][r32] = a0[r];
    }
    __syncthreads();

    // ---- LSTM pointwise: thread (b2, dd) owns (batch, dim bid*8+dd) ----
    {
      float xi = glds[b2][dd]      + bf2f(xr0);
      float xf = glds[b2][8+dd]    + bf2f(xr1);
      float xg = glds[b2][16+dd]   + bf2f(xr2);
      float xo = glds[b2][24+dd]   + bf2f(xr3);
      float cn = fmaf(sig2(xf), c_reg, sig2(xi)*tanh2(xg));
      c_reg = cn;
      float hv = sig2(xo)*tanh2(cn);
      float hp = __shfl_xor(hv, 1);                    // partner dim (dd^1)
      if (!(dd&1)) {
        u32 pk = (u32)f2bf(hv) | ((u32)f2bf(hp) << 16);
        st_u((u32*)(H2 + (size_t)(t+1)*32768 + (size_t)bid*512 + (size_t)b2*8) + (dd>>1), pk);
      }
    }
    if (t < 30) { gen++; gbar(flags, bid, gen); }
  }
}

// ---------------- workspace offsets (bytes, 256-aligned) ----------------
#define OFF_H    1024u           // 2,097,152  bf16 H2 (32,64,64,8); slot0 zeroed
#define OFF_UV   2098176u        // 6,422,528  bf16 (64,196,256)
#define OFF_X    8520704u        // 1,015,808  bf16 (1984,256)
#define OFF_XG   9536512u        // 8,126,464  bf16 (31,64,2048); Hl 2MB overlay post-decoder
#define OFF_GH   17662976u       // 15,360,000 bf16 embed
#define OFF_EMB  OFF_GH
#define OFF_WH   33915904u       // flags 4KB + ctxB (31,64,128) bf16 at +8192
#define OFF_E    35947520u       // 1,015,808  bf16 (1984,256)
#define OFF_VB   36963328u       // 3,211,264  bf16 V (pre-decoder); WcB bf16 512KB overlay
#define OFF_WIH  40174592u       // 1,572,864  bf16 Wih
#define OFF_WHH  41747456u       // 2,097,152  bf16 Whh
#define OFF_AWW  43844608u       // 262,144    bf16 attWw
#define OFF_AUW  44106752u       // 65,536     bf16 attUw
#define OFF_PRJ  44172288u       // 262,144    bf16 projw  -> end 44,434,432

extern "C" void kernel_launch(void* const* d_in, const int* in_sizes, int n_in,
                              void* d_out, int out_size, void* d_ws, size_t ws_size,
                              hipStream_t stream)
{
  const float* V      = (const float*)d_in[0];
  const int*   y      = (const int*)  d_in[1];
  const float* embed  = (const float*)d_in[2];
  const float* attWw  = (const float*)d_in[3];
  const float* attWb  = (const float*)d_in[4];
  const float* attUw  = (const float*)d_in[5];
  const float* attUb  = (const float*)d_in[6];
  const float* attvw  = (const float*)d_in[7];
  const float* attvb  = (const float*)d_in[8];
  const float* Wih    = (const float*)d_in[9];
  const float* Whh    = (const float*)d_in[10];
  const float* bih    = (const float*)d_in[11];
  const float* bhh    = (const float*)d_in[12];
  const float* projw  = (const float*)d_in[13];
  float* out = (float*)d_out;
  char* ws = (char*)d_ws;

  u16*   H2   = (u16*)  (ws + OFF_H);
  u16*   UVb  = (u16*)  (ws + OFF_UV);
  u16*   Xb   = (u16*)  (ws + OFF_X);
  u16*   Xg   = (u16*)  (ws + OFF_XG);
  u16*   Hl   = (u16*)  (ws + OFF_XG);   // reuses Xg region after decoder
  u32*   flags= (u32*)  (ws + OFF_WH);
  u16*   CtxB = (u16*)  (ws + OFF_WH + 8192);
  u16*   E    = (u16*)  (ws + OFF_E);
  u16*   Vb   = (u16*)  (ws + OFF_VB);
  u16*   WcB  = (u16*)  (ws + OFF_VB);   // reuses Vb space after UV gemm
  u16*   embB = (u16*)  (ws + OFF_EMB);
  u16*   WihB = (u16*)  (ws + OFF_WIH);
  u16*   WhhB = (u16*)  (ws + OFF_WHH);
  u16*   attWwB = (u16*)(ws + OFF_AWW);
  u16*   attUwB = (u16*)(ws + OFF_AUW);
  u16*   projB  = (u16*)(ws + OFF_PRJ);

  // zero H2 slot 0 (h0 = 0) and flags — re-done every call (ws is re-poisoned)
  hipMemsetAsync(ws + OFF_H, 0, 65536, stream);
  hipMemsetAsync(ws + OFF_WH, 0, 4096, stream);

  // all f32->bf16 converts + token gather in ONE dispatch (att weights pre-scaled)
  prep_all<<<13132, 256, 0, stream>>>(V, Wih, Whh, attWw, attUw, projw, embed, y,
                                      Vb, WihB, WhhB, attWwB, attUwB, projB, embB, Xb);

  // UV = TSCALE*(V @ attUw^T + attUb)  (bf16 out)   M=12544 N=256 K=128
  gemm_bt<<<196*2, 256, 0, stream>>>(Vb, 128, attUwB, 128, attUb, nullptr, TSCALE,
                                     UVb, 256, 12544, 256, 128, 196, 1);
  // WcB = bf16(Wih[:,256:384]) (overwrites Vb region — stream-ordered after UV gemm)
  prep_wih2b<<<1024, 256, 0, stream>>>(Wih, WcB);
  // Xg = X @ Wih[:, :256]^T + bih + bhh  (bf16 out)   M=1984 N=2048 K=256
  gemm_bt<<<31*16, 256, 0, stream>>>(Xb, 256, WihB, 384, bih, bhh, 1.0f,
                                     Xg, 2048, 1984, 2048, 256, 31, 1);

  decoder_steps<<<NB, 512, 0, stream>>>(V, attWb, attvw, attvb,
      WhhB, attWwB, WcB, H2, UVb, Xg, CtxB, flags);

  // H2 -> row-major Hl (1984,512) for the projection GEMM (overlays dead Xg)
  repack_h<<<1984, 256, 0, stream>>>(H2, Hl);

  // E = Hl @ projw^T (bf16 out)   M=1984 N=256 K=512
  gemm_bt<<<31*2, 256, 0, stream>>>(Hl, 512, projB, 512, nullptr, nullptr, 1.0f,
                                    E, 256, 1984, 256, 512, 31, 1);
  // logits = E @ embed^T -> d_out f32 with (s,b)->(b,s) row remap   M=1984 N=30000 K=256
  gemm_bt<<<31*235, 256, 0, stream>>>(E, 256, embB, 256, nullptr, nullptr, 1.0f,
                                      out, 30000, 1984, 30000, 256, 31, 2);
}

// Round 6
// 959.302 us; speedup vs baseline: 1.0495x; 1.0428x over previous
//
#include <hip/hip_runtime.h>
#include <stdint.h>

typedef unsigned short u16;
typedef uint32_t u32;
typedef short s16x8 __attribute__((ext_vector_type(8)));
typedef float f32x4 __attribute__((ext_vector_type(4)));

#define DEV __device__ __forceinline__

// 2*log2(e): tanh(x) = 1 - 2/(exp2(C*x)+1)
#define TSCALE 2.885390082f

DEV float bf2f(u16 h){ union{u32 u; float f;} x; x.u = ((u32)h)<<16; return x.f; }
DEV u16 f2bf(float f){ union{float f; u32 u;} x; x.f = f; u32 u = x.u;
  return (u16)((u + 0x7fffu + ((u>>16)&1u))>>16); }
DEV float bflo(u32 w){ union{u32 u; float f;} x; x.u = w<<16; return x.f; }
DEV float bfhi(u32 w){ union{u32 u; float f;} x; x.u = w & 0xffff0000u; return x.f; }

DEV float exp2_fast(float x){ return __builtin_amdgcn_exp2f(x); }
DEV float rcp_fast(float x){ return __builtin_amdgcn_rcpf(x); }
DEV float tanh2(float x){ float t = exp2_fast(TSCALE*x);
  return fmaf(-2.f, rcp_fast(t + 1.f), 1.f); }
DEV float sig2(float x){ return rcp_fast(1.f + exp2_fast(-1.442695041f*x)); }

// device-coherent (agent-scope, write-through) accessors — exchange stores + flags.
DEV u32   ld_u(const u32* p){ return __hip_atomic_load(p, __ATOMIC_RELAXED, __HIP_MEMORY_SCOPE_AGENT); }
DEV void  st_u(u32* p, u32 v){ __hip_atomic_store(p, v, __ATOMIC_RELAXED, __HIP_MEMORY_SCOPE_AGENT); }

// ---------------- fused prep: all f32->bf16 converts + token gather ----------------
DEV void cvt4(const float* __restrict__ src, u16* __restrict__ dst, int i, float scale){
  float4 v = ((const float4*)src)[i];
  ushort4 o; o.x = f2bf(v.x*scale); o.y = f2bf(v.y*scale); o.z = f2bf(v.z*scale); o.w = f2bf(v.w*scale);
  ((ushort4*)dst)[i] = o;
}
__global__ void prep_all(
    const float* __restrict__ V, const float* __restrict__ Wih, const float* __restrict__ Whh,
    const float* __restrict__ attWw, const float* __restrict__ attUw, const float* __restrict__ projw,
    const float* __restrict__ embed, const int* __restrict__ y,
    u16* __restrict__ Vb, u16* __restrict__ WihB, u16* __restrict__ WhhB,
    u16* __restrict__ attWwB, u16* __restrict__ attUwB, u16* __restrict__ projB,
    u16* __restrict__ embB, u16* __restrict__ Xb)
{
  int blk = blockIdx.x, tid = threadIdx.x;
  if      (blk < 1568)  cvt4(V,     Vb,     blk*256 + tid, 1.0f);
  else if (blk < 2336)  cvt4(Wih,   WihB,   (blk-1568)*256 + tid, 1.0f);
  else if (blk < 3360)  cvt4(Whh,   WhhB,   (blk-2336)*256 + tid, 1.0f);
  else if (blk < 3488)  cvt4(attWw, attWwB, (blk-3360)*256 + tid, TSCALE);
  else if (blk < 3520)  cvt4(attUw, attUwB, (blk-3488)*256 + tid, TSCALE);
  else if (blk < 3648)  cvt4(projw, projB,  (blk-3520)*256 + tid, 1.0f);
  else if (blk < 11148) cvt4(embed, embB,   (blk-3648)*256 + tid, 1.0f);
  else {
    int r = blk - 11148;                 // 0..1983 : row s*64+b
    int s = r>>6, b = r&63;
    int tok = y[b*32 + s];
    Xb[(size_t)r*256 + tid] = f2bf(embed[(size_t)tok*256 + tid]);
  }
}

// ---- extract Wih[:,256:384] as bf16 (2048 x 128) ----
__global__ void prep_wih2b(const float* __restrict__ Wih, u16* __restrict__ Wc){
  int idx = blockIdx.x*256 + threadIdx.x;      // 2048*128 = 262144
  int j = idx>>7, k = idx&127;
  Wc[idx] = f2bf(Wih[(size_t)j*384 + 256 + k]);
}

// ---- repack H2[t][q][b][8] (t=1..31) -> Hl[(s*64+b)][512] row-major ----
__global__ void repack_h(const u16* __restrict__ H2, u16* __restrict__ Hl){
  int r = blockIdx.x;                // 0..1983 : row s*64+b
  int s = r>>6, b = r&63;
  int tid = threadIdx.x;             // 256 threads, each one u32 (2 cols)
  u32 v = *((const u32*)(H2 + (size_t)(s+1)*32768 + (size_t)(tid>>2)*512 + (size_t)b*8) + (tid&3));
  ((u32*)(Hl + (size_t)r*512))[tid] = v;
}

// ---------------- C = A * B^T (+bias) bf16 MFMA GEMM, 64x128 tile ----------------
// mode 0: f32 out; 1: bf16 out; 2: f32 out with row remap (r=s*64+b -> b*31+s)
// XCD-bijective block swizzle (m204): contiguous bid-ranges per XCD -> L2 locality.
__global__ __launch_bounds__(256) void gemm_bt(
    const u16* __restrict__ A, int lda,
    const u16* __restrict__ B, int ldb,
    const float* __restrict__ bias1, const float* __restrict__ bias2, float bscale,
    void* __restrict__ C, int ldc,
    int M, int N, int K, int Mt, int mode)
{
  __shared__ __align__(16) u16 As[64*64];
  __shared__ __align__(16) u16 Bs[128*64];
  int nwg = (int)gridDim.x;
  int b0 = blockIdx.x;
  int qq = nwg >> 3, rr = nwg & 7;
  int bswz;
  if (qq == 0) bswz = b0;
  else {
    int xcd = b0 & 7, i = b0 >> 3;
    bswz = (xcd < rr) ? (xcd*(qq+1) + i) : (rr*(qq+1) + (xcd - rr)*qq + i);
  }
  int mt = bswz % Mt, nt = bswz / Mt;
  int m0 = mt*64, n0 = nt*128;
  int tid = threadIdx.x, wave = tid>>6, lane = tid&63;
  int lrow = lane>>3, lcol = (lane&7)*8;
  f32x4 acc[2][4];
  #pragma unroll
  for (int i=0;i<2;i++)
    #pragma unroll
    for (int j=0;j<4;j++) acc[i][j] = (f32x4){0,0,0,0};
  int wm = (wave>>1)*32, wn = (wave&1)*64;
  int fr = lane&15, fk = (lane>>4)*8;
  for (int k0 = 0; k0 < K; k0 += 64) {
    __syncthreads();
    #pragma unroll
    for (int i = 0; i < 2; i++) {
      int ci = wave + i*4;
      int row = ci*8 + lrow;
      const u16* g = A + (size_t)(m0+row)*lda + k0 + lcol;
      __builtin_amdgcn_global_load_lds(
        (const __attribute__((address_space(1))) u32*)g,
        (__attribute__((address_space(3))) u32*)&As[ci*512], 16, 0, 0);
    }
    #pragma unroll
    for (int i = 0; i < 4; i++) {
      int ci = wave + i*4;
      int row = ci*8 + lrow;
      int gr = n0 + row; gr = gr < N ? gr : N-1;
      const u16* g = B + (size_t)gr*ldb + k0 + lcol;
      __builtin_amdgcn_global_load_lds(
        (const __attribute__((address_space(1))) u32*)g,
        (__attribute__((address_space(3))) u32*)&Bs[ci*512], 16, 0, 0);
    }
    __syncthreads();
    #pragma unroll
    for (int kk = 0; kk < 2; kk++) {
      s16x8 af[2], bfv[4];
      #pragma unroll
      for (int mi=0; mi<2; mi++)
        af[mi] = *(const s16x8*)&As[(wm + mi*16 + fr)*64 + kk*32 + fk];
      #pragma unroll
      for (int ni=0; ni<4; ni++)
        bfv[ni] = *(const s16x8*)&Bs[(wn + ni*16 + fr)*64 + kk*32 + fk];
      #pragma unroll
      for (int mi=0; mi<2; mi++)
        #pragma unroll
        for (int ni=0; ni<4; ni++)
          acc[mi][ni] = __builtin_amdgcn_mfma_f32_16x16x32_bf16(af[mi], bfv[ni], acc[mi][ni], 0,0,0);
    }
  }
  #pragma unroll
  for (int mi=0; mi<2; mi++)
    #pragma unroll
    for (int ni=0; ni<4; ni++) {
      int col = n0 + wn + ni*16 + (lane&15);
      if (col >= N) continue;
      float bv = 0.0f;
      if (bias1) bv += bias1[col];
      if (bias2) bv += bias2[col];
      bv *= bscale;
      int rbase = m0 + wm + mi*16 + ((lane>>4)<<2);
      #pragma unroll
      for (int r=0; r<4; r++) {
        int row = rbase + r;
        float v = acc[mi][ni][r] + bv;
        if (mode == 0) ((float*)C)[(size_t)row*ldc + col] = v;
        else if (mode == 1) ((u16*)C)[(size_t)row*ldc + col] = f2bf(v);
        else { int orow = (row&63)*31 + (row>>6); ((float*)C)[(size_t)orow*ldc + col] = v; }
      }
    }
}

// ---------------- logits: n-stationary persistent GEMM ----------------
// out[b*31+s][col] = E[(s*64+b)] . embB[col], E (1984,256), embB (30000,256).
// 235 blocks each own 128 cols; embB slab staged to LDS ONCE (64KB), A-tile
// (32KB) restaged per m-iter. LDS is chunk-transposed: 16B unit (c,row) at
// linear index c*NR+row -> ds_read over 16 consecutive rows = unit-stride-1
// (conflict-free) AND global_load_lds dest stays wave-uniform + lane*16.
__global__ __launch_bounds__(256) void logits_nstat(
    const u16* __restrict__ E,      // (1984,256)
    const u16* __restrict__ Bm,     // (30000,256)
    float* __restrict__ C)          // (1984,30000) remapped rows
{
  __shared__ __align__(16) u16 Bs[4096*8];   // 64KB: unit u = c*128 + row
  __shared__ __align__(16) u16 As[2048*8];   // 32KB: unit u = c*64  + row
  int tid = threadIdx.x, wave = tid>>6, lane = tid&63;
  int fr = lane&15, fkq = lane>>4;
  int n0 = blockIdx.x*128;
  // stage B slab once: 64 issues (16/wave); issue e: chunk c=e>>1, rows r0..r0+63
  for (int j=0;j<16;j++){
    int e = wave*16 + j;
    int c = e>>1, r0 = (e&1)*64;
    int gr = n0 + r0 + lane; if (gr > 29999) gr = 29999;
    const u16* g = Bm + (size_t)gr*256 + c*8;
    __builtin_amdgcn_global_load_lds(
      (const __attribute__((address_space(1))) u32*)g,
      (__attribute__((address_space(3))) u32*)&Bs[((size_t)c*128 + r0)*8], 16, 0, 0);
  }
  f32x4 acc[4][2];
  for (int mt=0; mt<31; mt++){
    __syncthreads();          // prev iter finished reading As
    // stage A tile (64 rows x 256 k): 32 issues, 8/wave: chunk c = wave*8+j
    #pragma unroll
    for (int j=0;j<8;j++){
      int c = wave*8 + j;
      const u16* g = E + (size_t)(mt*64 + lane)*256 + c*8;
      __builtin_amdgcn_global_load_lds(
        (const __attribute__((address_space(1))) u32*)g,
        (__attribute__((address_space(3))) u32*)&As[((size_t)c*64 + lane)*8], 16, 0, 0);
    }
    __syncthreads();          // drains vmcnt (A this iter; B on first iter)
    #pragma unroll
    for (int mi=0;mi<4;mi++)
      #pragma unroll
      for (int ni=0;ni<2;ni++) acc[mi][ni]=(f32x4){0,0,0,0};
    #pragma unroll
    for (int kk=0;kk<8;kk++){
      int c = kk*4 + fkq;
      s16x8 bfv[2], af[4];
      #pragma unroll
      for (int ni=0;ni<2;ni++)
        bfv[ni] = *(const s16x8*)&Bs[((size_t)c*128 + wave*32 + ni*16 + fr)*8];
      #pragma unroll
      for (int mi=0;mi<4;mi++)
        af[mi] = *(const s16x8*)&As[((size_t)c*64 + mi*16 + fr)*8];
      #pragma unroll
      for (int mi=0;mi<4;mi++)
        #pragma unroll
        for (int ni=0;ni<2;ni++)
          acc[mi][ni] = __builtin_amdgcn_mfma_f32_16x16x32_bf16(af[mi], bfv[ni], acc[mi][ni], 0,0,0);
    }
    // write: col = n0 + wave*32 + ni*16 + fr ; local m-row lm = mi*16 + fkq*4 + r
    // output row remap: (s*64+b) -> b*31+s with s=mt, b=lm
    #pragma unroll
    for (int mi=0;mi<4;mi++)
      #pragma unroll
      for (int ni=0;ni<2;ni++){
        int col = n0 + wave*32 + ni*16 + fr;
        if (col < 30000){
          #pragma unroll
          for (int r=0;r<4;r++){
            int lm = mi*16 + fkq*4 + r;
            C[(size_t)(lm*31 + mt)*30000 + col] = acc[mi][ni][r];
          }
        }
      }
  }
}

// ---------------- persistent recurrence kernel (64 blocks x 512 thr, role-alternating) ----------------
#define NB 64

// all-report flag barrier: producers drain write-through stores (s_waitcnt 0)
// before posting; each block's flag in its own 64B line; 64 lanes poll 64 lines.
DEV void gbar(u32* flags, int bid, unsigned g){
  __asm__ volatile("" ::: "memory");
  __builtin_amdgcn_s_waitcnt(0);
  __syncthreads();
  if (threadIdx.x == 0) st_u(&flags[bid*16], g);
  if (threadIdx.x < 64) {
    for (;;) {
      u32 a = ld_u(&flags[threadIdx.x*16]);
      if (__all(a >= g)) break;
      __builtin_amdgcn_s_sleep(1);
    }
  }
  __syncthreads();
  __asm__ volatile("" ::: "memory");
}

// ROUND-3 CONFIGURATION (measured 562.9us) — verbatim revert.
// 512 threads, 8 waves (2/SIMD):
//   waves 0-3: X' role (af prefetch BEFORE sync1, pre-fired h-MFMAs, post-bar1 tail) + Y share
//   waves 4-7: hls/Xg staging + Y share
__global__ __launch_bounds__(512, 1) void decoder_steps(
    const float* __restrict__ V,      // (64,196,128) f32, cached
    const float* __restrict__ attWb,  // (256) f32 (scaled in-kernel)
    const float* __restrict__ attvw,  // (256) f32
    const float* __restrict__ attvb,  // (1)
    const u16* __restrict__ WhhB,     // (2048,512) bf16
    const u16* __restrict__ attWwB,   // (256,512) bf16, PRE-SCALED by TSCALE
    const u16* __restrict__ WcB,      // (2048,128) bf16 = Wih[:,256:384]
    u16* __restrict__ H2,             // (32,64,64,8) bf16 exchange [t][q][b][d]
    const u16* __restrict__ UV,       // (64,196,256) bf16, PRE-SCALED by TSCALE
    const u16* __restrict__ Xg,       // (31,64,2048) bf16, cached (prior kernel)
    u16* __restrict__ CtxB,           // (31,64,128) bf16 exchange
    u32* __restrict__ flags)
{
  int bid = blockIdx.x, tid = threadIdx.x;
  int wave = tid>>6, lane = tid&63;
  int fr = lane&15, fkq = lane>>4;

  __shared__ __align__(16) u16 Wlds[32][648];   // 32 gate rows x 640 (pad 8)
  __shared__ __align__(16) u16 Xglds[64][32];   // Xg slice [b][gate*8+d]
  __shared__ float hls[512];
  __shared__ float whs[256];
  __shared__ float vws[256];
  __shared__ float esc[200];
  __shared__ float red1;
  __shared__ float part[512];

  // ---- prologue: stage this block's 32 gate rows of [Whh | Wc] into LDS ----
  {
    int r = tid>>4, p = tid&15;                      // 32 rows x 16 threads/row
    int grow = ((r>>3)<<9) + bid*8 + (r&7);          // gate*512 + q*8 + dim
    #pragma unroll
    for (int i=0;i<5;i++){
      int k = p*40 + i*8;
      const u16* src = (k < 512) ? (WhhB + (size_t)grow*512 + k)
                                 : (WcB  + (size_t)grow*128 + (k-512));
      *(s16x8*)&Wlds[r][k] = *(const s16x8*)src;
    }
  }
  if (tid < 256) vws[tid] = attvw[tid];
  float vb = attvb[0];
  float c_reg[4] = {0.f,0.f,0.f,0.f};
  unsigned gen = 0;
  __syncthreads();

  int br = wave*16 + fr;   // batch row this lane owns in the X' MFMA (waves 0-3)

  for (int t = 0; t < 31; t++) {
    // ---- waves 0-3: X' A-frag prefetch; waves 4-7: hls + Xg staging ----
    s16x8 af[16];
    s16x8 xg;
    if (tid < 256) {
      const u16* Hbase = H2 + (size_t)t*32768 + (size_t)br*8;
      #pragma unroll
      for (int kt=0;kt<16;kt++) af[kt] = *(const s16x8*)(Hbase + (size_t)(kt*4+fkq)*512);
    } else {
      int t2 = tid - 256;
      u32 hv = *((const u32*)(H2 + (size_t)t*32768 + (size_t)(t2>>2)*512 + (size_t)bid*8) + (t2&3));
      hls[2*t2]   = bflo(hv);
      hls[2*t2+1] = bfhi(hv);
      xg = *(const s16x8*)(Xg + (size_t)t*131072 + (size_t)(t2>>2)*2048 + (size_t)(t2&3)*512 + (size_t)bid*8);
    }
    __syncthreads();

    // ---- wh (pre-scaled): thread pair (a=tid>>1) splits k in halves ----
    {
      int a_ = tid>>1, kh = (tid&1)*256;
      const u32* wr = (const u32*)(attWwB + (size_t)a_*512 + kh);
      float acc = (tid&1) ? 0.f : TSCALE * attWb[a_];
      #pragma unroll 4
      for (int k=0;k<256;k+=8){
        u32 w0 = wr[(k>>1)+0], w1 = wr[(k>>1)+1], w2 = wr[(k>>1)+2], w3 = wr[(k>>1)+3];
        float4 h0 = *(const float4*)&hls[kh+k];
        float4 h1 = *(const float4*)&hls[kh+k+4];
        acc = fmaf(bflo(w0), h0.x, acc); acc = fmaf(bfhi(w0), h0.y, acc);
        acc = fmaf(bflo(w1), h0.z, acc); acc = fmaf(bfhi(w1), h0.w, acc);
        acc = fmaf(bflo(w2), h1.x, acc); acc = fmaf(bfhi(w2), h1.y, acc);
        acc = fmaf(bflo(w3), h1.z, acc); acc = fmaf(bfhi(w3), h1.w, acc);
      }
      acc += __shfl_xor(acc, 1);
      if (!(tid&1)) whs[a_] = acc;
    }

    // ---- waves 0-3: fire h-part MFMAs into matrix pipe (consumed post-bar1) ----
    f32x4 a0 = (f32x4){0,0,0,0}, a1 = (f32x4){0,0,0,0};
    if (tid < 256) {
      #pragma unroll
      for (int kt=0;kt<16;kt++){
        s16x8 b0 = *(const s16x8*)&Wlds[fr][kt*32 + fkq*8];
        s16x8 b1 = *(const s16x8*)&Wlds[16+fr][kt*32 + fkq*8];
        a0 = __builtin_amdgcn_mfma_f32_16x16x32_bf16(af[kt], b0, a0, 0,0,0);
        a1 = __builtin_amdgcn_mfma_f32_16x16x32_bf16(af[kt], b1, a1, 0,0,0);
      }
      __builtin_amdgcn_sched_barrier(0);
    }
    __syncthreads();

    // ---- scores: half-row per thread (n=tid>>1, 128 dims), shfl pair-combine.
    //      no max-sub: |e| <= sum|vw| ~ 4.1 by construction ----
    if (tid < 392) {
      int n = tid>>1, kh = (tid&1)*128;
      const u32* uvp = (const u32*)(UV + ((size_t)bid*196 + n)*256 + kh);
      float e0 = 0.0f, e1 = 0.0f;
      #pragma unroll 4
      for (int a = 0; a < 128; a += 4) {
        u32 uw0 = uvp[(a>>1)], uw1 = uvp[(a>>1)+1];
        float4 w4 = *(const float4*)&whs[kh+a];
        float4 v4 = *(const float4*)&vws[kh+a];
        float t0 = exp2_fast(w4.x + bflo(uw0));
        float t1 = exp2_fast(w4.y + bfhi(uw0));
        float t2 = exp2_fast(w4.z + bflo(uw1));
        float t3 = exp2_fast(w4.w + bfhi(uw1));
        e0 = fmaf(v4.x, fmaf(-2.f, rcp_fast(t0+1.f), 1.f), e0);
        e1 = fmaf(v4.y, fmaf(-2.f, rcp_fast(t1+1.f), 1.f), e1);
        e0 = fmaf(v4.z, fmaf(-2.f, rcp_fast(t2+1.f), 1.f), e0);
        e1 = fmaf(v4.w, fmaf(-2.f, rcp_fast(t3+1.f), 1.f), e1);
      }
      float e = e0 + e1;
      e += __shfl_xor(e, 1);
      if (!(tid&1)) esc[n] = exp2_fast(1.442695041f*(e + vb));
    }
    // stage Xg -> LDS (waves 4-7; consumed post-bar1, ordered by gbar's syncthreads)
    if (tid >= 256) {
      int t2 = tid - 256;
      *(s16x8*)&Xglds[t2>>2][(t2&3)*8] = xg;
    }
    __syncthreads();

    // ---- sum (wave 0) runs concurrently with 4-way ctx partials (all waves) ----
    if (tid < 64) {
      float s = esc[tid] + esc[64+tid] + esc[128+tid];
      if (tid < 4)  s += esc[192+tid];
      #pragma unroll
      for (int off=32; off>=1; off>>=1) s += __shfl_xor(s, off);
      if (tid==0) red1 = s;
    }
    {
      int k = tid&127, q4 = tid>>7;
      const float* vp = V + ((size_t)bid*196 + q4*49)*128 + k;
      float a = 0.f;
      for (int n2=0; n2<49; n2++) a = fmaf(esc[q4*49+n2], vp[(size_t)n2*128], a);
      part[tid] = a;
    }
    __syncthreads();

    // ---- combine + normalize + publish ctx (bf16 pairs) ----
    if (tid < 64) {
      float inv = rcp_fast(red1);
      float c0 = (part[2*tid]   + part[128+2*tid] + part[256+2*tid] + part[384+2*tid]) * inv;
      float c1 = (part[2*tid+1] + part[129+2*tid] + part[257+2*tid] + part[385+2*tid]) * inv;
      u32 pk = (u32)f2bf(c0) | ((u32)f2bf(c1) << 16);
      st_u((u32*)(CtxB + (size_t)t*8192 + (size_t)bid*128) + tid, pk);
    }
    gen++; gbar(flags, bid, gen);

    // ---- X' tail (waves 0-3): ctx MFMAs + LSTM pointwise ----
    if (tid < 256) {
      const u16* Crow = CtxB + (size_t)t*8192 + (size_t)br*128 + fkq*8;
      #pragma unroll
      for (int kt=0;kt<4;kt++){
        s16x8 cf = *(const s16x8*)(Crow + kt*32);
        s16x8 b0 = *(const s16x8*)&Wlds[fr][(16+kt)*32 + fkq*8];
        s16x8 b1 = *(const s16x8*)&Wlds[16+fr][(16+kt)*32 + fkq*8];
        a0 = __builtin_amdgcn_mfma_f32_16x16x32_bf16(cf, b0, a0, 0,0,0);
        a1 = __builtin_amdgcn_mfma_f32_16x16x32_bf16(cf, b1, a1, 0,0,0);
      }
      // acc mapping: col c=lane&15 -> gate row; row = wave*16 + fkq*4 + r -> batch
      int c = fr;
      int xr0 = ((c>>3)&1)*8 + (c&7);          // Xglds row for tile0 (i|f)
      float v0[4], v1[4], s0[4], s1[4];
      #pragma unroll
      for (int r=0;r<4;r++){
        int b_r = wave*16 + fkq*4 + r;
        v0[r] = a0[r] + bf2f(Xglds[b_r][xr0]);        // i (c<8) / f (c>=8)
        v1[r] = a1[r] + bf2f(Xglds[b_r][16+xr0]);     // g (c<8) / o (c>=8)
      }
      #pragma unroll
      for (int r=0;r<4;r++){ s0[r] = __shfl_xor(v0[r], 8); s1[r] = __shfl_xor(v1[r], 8); }
      if (c < 8) {
        #pragma unroll
        for (int r=0;r<4;r++){
          int b_r = wave*16 + fkq*4 + r;
          float ig = sig2(v0[r]);
          float fg = sig2(s0[r]);
          float gg = tanh2(v1[r]);
          float og = sig2(s1[r]);
          float cn = fmaf(fg, c_reg[r], ig*gg);
          c_reg[r] = cn;
          float hvv = og * tanh2(cn);
          float hp = __shfl_xor(hvv, 1);              // partner dim (c^1)
          if (!(c&1)) {
            u32 pk = (u32)f2bf(hvv) | ((u32)f2bf(hp) << 16);
            st_u((u32*)(H2 + (size_t)(t+1)*32768 + (size_t)bid*512 + (size_t)b_r*8) + (c>>1), pk);
          }
        }
      }
    }
    if (t < 30) { gen++; gbar(flags, bid, gen); }
  }
}

// ---------------- workspace offsets (bytes, 256-aligned) ----------------
#define OFF_H    1024u           // 2,097,152  bf16 H2 (32,64,64,8); slot0 zeroed
#define OFF_UV   2098176u        // 6,422,528  bf16 (64,196,256)
#define OFF_X    8520704u        // 1,015,808  bf16 (1984,256)
#define OFF_XG   9536512u        // 8,126,464  bf16 (31,64,2048); Hl 2MB overlay post-decoder
#define OFF_GH   17662976u       // 15,360,000 bf16 embed
#define OFF_EMB  OFF_GH
#define OFF_WH   33915904u       // flags 4KB + ctxB (31,64,128) bf16 at +8192
#define OFF_E    35947520u       // 1,015,808  bf16 (1984,256)
#define OFF_VB   36963328u       // 3,211,264  bf16 V (pre-decoder); WcB bf16 512KB overlay
#define OFF_WIH  40174592u       // 1,572,864  bf16 Wih
#define OFF_WHH  41747456u       // 2,097,152  bf16 Whh
#define OFF_AWW  43844608u       // 262,144    bf16 attWw
#define OFF_AUW  44106752u       // 65,536     bf16 attUw
#define OFF_PRJ  44172288u       // 262,144    bf16 projw  -> end 44,434,432

extern "C" void kernel_launch(void* const* d_in, const int* in_sizes, int n_in,
                              void* d_out, int out_size, void* d_ws, size_t ws_size,
                              hipStream_t stream)
{
  const float* V      = (const float*)d_in[0];
  const int*   y      = (const int*)  d_in[1];
  const float* embed  = (const float*)d_in[2];
  const float* attWw  = (const float*)d_in[3];
  const float* attWb  = (const float*)d_in[4];
  const float* attUw  = (const float*)d_in[5];
  const float* attUb  = (const float*)d_in[6];
  const float* attvw  = (const float*)d_in[7];
  const float* attvb  = (const float*)d_in[8];
  const float* Wih    = (const float*)d_in[9];
  const float* Whh    = (const float*)d_in[10];
  const float* bih    = (const float*)d_in[11];
  const float* bhh    = (const float*)d_in[12];
  const float* projw  = (const float*)d_in[13];
  float* out = (float*)d_out;
  char* ws = (char*)d_ws;

  u16*   H2   = (u16*)  (ws + OFF_H);
  u16*   UVb  = (u16*)  (ws + OFF_UV);
  u16*   Xb   = (u16*)  (ws + OFF_X);
  u16*   Xg   = (u16*)  (ws + OFF_XG);
  u16*   Hl   = (u16*)  (ws + OFF_XG);   // reuses Xg region after decoder
  u32*   flags= (u32*)  (ws + OFF_WH);
  u16*   CtxB = (u16*)  (ws + OFF_WH + 8192);
  u16*   E    = (u16*)  (ws + OFF_E);
  u16*   Vb   = (u16*)  (ws + OFF_VB);
  u16*   WcB  = (u16*)  (ws + OFF_VB);   // reuses Vb space after UV gemm
  u16*   embB = (u16*)  (ws + OFF_EMB);
  u16*   WihB = (u16*)  (ws + OFF_WIH);
  u16*   WhhB = (u16*)  (ws + OFF_WHH);
  u16*   attWwB = (u16*)(ws + OFF_AWW);
  u16*   attUwB = (u16*)(ws + OFF_AUW);
  u16*   projB  = (u16*)(ws + OFF_PRJ);

  // zero H2 slot 0 (h0 = 0) and flags — re-done every call (ws is re-poisoned)
  hipMemsetAsync(ws + OFF_H, 0, 65536, stream);
  hipMemsetAsync(ws + OFF_WH, 0, 4096, stream);

  // all f32->bf16 converts + token gather in ONE dispatch (att weights pre-scaled)
  prep_all<<<13132, 256, 0, stream>>>(V, Wih, Whh, attWw, attUw, projw, embed, y,
                                      Vb, WihB, WhhB, attWwB, attUwB, projB, embB, Xb);

  // UV = TSCALE*(V @ attUw^T + attUb)  (bf16 out)   M=12544 N=256 K=128
  gemm_bt<<<196*2, 256, 0, stream>>>(Vb, 128, attUwB, 128, attUb, nullptr, TSCALE,
                                     UVb, 256, 12544, 256, 128, 196, 1);
  // WcB = bf16(Wih[:,256:384]) (overwrites Vb region — stream-ordered after UV gemm)
  prep_wih2b<<<1024, 256, 0, stream>>>(Wih, WcB);
  // Xg = X @ Wih[:, :256]^T + bih + bhh  (bf16 out)   M=1984 N=2048 K=256
  gemm_bt<<<31*16, 256, 0, stream>>>(Xb, 256, WihB, 384, bih, bhh, 1.0f,
                                     Xg, 2048, 1984, 2048, 256, 31, 1);

  decoder_steps<<<NB, 512, 0, stream>>>(V, attWb, attvw, attvb,
      WhhB, attWwB, WcB, H2, UVb, Xg, CtxB, flags);

  // H2 -> row-major Hl (1984,512) for the projection GEMM (overlays dead Xg)
  repack_h<<<1984, 256, 0, stream>>>(H2, Hl);

  // E = Hl @ projw^T (bf16 out)   M=1984 N=256 K=512
  gemm_bt<<<31*2, 256, 0, stream>>>(Hl, 512, projB, 512, nullptr, nullptr, 1.0f,
                                    E, 256, 1984, 256, 512, 31, 1);
  // logits = E @ embed^T -> d_out f32, n-stationary (B-slab LDS-resident)
  logits_nstat<<<235, 256, 0, stream>>>(E, embB, out);
}